// Round 1
// baseline (240034.766 us; speedup 1.0000x reference)
//
#include <hip/hip_runtime.h>
#include <hip/hip_cooperative_groups.h>
#include <math.h>

namespace cg = cooperative_groups;

#define H 2048
#define S 8192
#define RPB 8            // hidden rows per block
#define NBLK (H / RPB)   // 256 blocks = 256 CUs

// ---------------------------------------------------------------------------
// GEMM: U[t][j] = sum_k X[t][k] * Wxh[j][k]   (both row-major, NT layout)
// 64x64 tile, BK=16, 256 threads, 4x4 accumulator per thread, fp32 vector ALU.
// ---------------------------------------------------------------------------
__global__ __launch_bounds__(256) void gemm_xw(const float* __restrict__ X,
                                               const float* __restrict__ W,
                                               float* __restrict__ U) {
    __shared__ float As[16][64];   // [k][t]
    __shared__ float Bs[16][64];   // [k][j]
    const int tid = threadIdx.x;
    const int t0 = blockIdx.x * 64;
    const int j0 = blockIdx.y * 64;
    const int tx = tid & 15, ty = tid >> 4;

    float acc[4][4] = {};
    const int lr = tid >> 2;        // 0..63 tile row
    const int lk = (tid & 3) * 4;   // 0,4,8,12 k-offset

    for (int k0 = 0; k0 < H; k0 += 16) {
        float4 a = *(const float4*)&X[(size_t)(t0 + lr) * H + k0 + lk];
        float4 b = *(const float4*)&W[(size_t)(j0 + lr) * H + k0 + lk];
        As[lk + 0][lr] = a.x; As[lk + 1][lr] = a.y; As[lk + 2][lr] = a.z; As[lk + 3][lr] = a.w;
        Bs[lk + 0][lr] = b.x; Bs[lk + 1][lr] = b.y; Bs[lk + 2][lr] = b.z; Bs[lk + 3][lr] = b.w;
        __syncthreads();
#pragma unroll
        for (int kk = 0; kk < 16; ++kk) {
            float4 av = *(const float4*)&As[kk][ty * 4];
            float4 bv = *(const float4*)&Bs[kk][tx * 4];
            float aa[4] = {av.x, av.y, av.z, av.w};
            float bb[4] = {bv.x, bv.y, bv.z, bv.w};
#pragma unroll
            for (int i = 0; i < 4; ++i)
#pragma unroll
                for (int j = 0; j < 4; ++j)
                    acc[i][j] += aa[i] * bb[j];
        }
        __syncthreads();
    }
#pragma unroll
    for (int i = 0; i < 4; ++i) {
        float4 v = {acc[i][0], acc[i][1], acc[i][2], acc[i][3]};
        *(float4*)&U[(size_t)(t0 + ty * 4 + i) * H + j0 + tx * 4] = v;
    }
}

// ---------------------------------------------------------------------------
// Persistent recurrent kernel. out[0 .. S*H) initially holds U (from gemm_xw)
// and is overwritten in place with h_t; out[S*H .. S*H+H) receives h_T.
// hbuf: 2*H floats in d_ws (double buffer for h).
// Each block: 8 rows of W_hh staged in LDS (64 KB); per step reads full
// h_prev (8 KB) into LDS, computes 8 dots (32 lanes/row), grid.sync().
// ---------------------------------------------------------------------------
__global__ __launch_bounds__(256) void rnn_recur(float* __restrict__ out,
                                                 const float* __restrict__ Whh,
                                                 const float* __restrict__ bias,
                                                 float* __restrict__ hbuf) {
    __shared__ float Wl[RPB * H];   // 64 KB: this block's 8 rows of W_hh
    __shared__ float hs[H];         // 8 KB: h_{t-1}
    const int tid = threadIdx.x;
    const int r0 = blockIdx.x * RPB;

    // Stage W rows into LDS (once).
    {
        const float4* src = (const float4*)&Whh[(size_t)r0 * H];
        float4* dst = (float4*)Wl;
        for (int i = tid; i < RPB * H / 4; i += 256) dst[i] = src[i];
    }
    // Zero our slice of h0.
    if (tid < RPB) hbuf[r0 + tid] = 0.0f;

    cg::grid_group grid = cg::this_grid();
    grid.sync();

    const int g    = tid >> 5;   // row group 0..7 (aligned 32-lane segments)
    const int lane = tid & 31;
    const int row  = r0 + g;
    const float bb = bias[row];
    const float4* wr = (const float4*)&Wl[g * H];
    const float4* hv = (const float4*)hs;

    for (int t = 0; t < S; ++t) {
        // Broadcast h_prev into LDS (512 float4, 2 per thread).
        const float4* hp = (const float4*)&hbuf[(t & 1) * H];
        ((float4*)hs)[tid]       = hp[tid];
        ((float4*)hs)[tid + 256] = hp[tid + 256];
        __syncthreads();

        float dot = 0.f;
#pragma unroll
        for (int i = 0; i < 16; ++i) {
            float4 w  = wr[lane + i * 32];
            float4 h4 = hv[lane + i * 32];
            dot += w.x * h4.x + w.y * h4.y + w.z * h4.z + w.w * h4.w;
        }
#pragma unroll
        for (int off = 16; off; off >>= 1)
            dot += __shfl_down(dot, off, 32);

        if (lane == 0) {
            float val = tanhf(dot + out[(size_t)t * H + row] + bb);
            out[(size_t)t * H + row] = val;                 // overwrite U with h_t
            hbuf[((t + 1) & 1) * H + row] = val;            // publish for next step
            if (t == S - 1) out[(size_t)S * H + row] = val; // h_T
        }
        grid.sync();
    }
}

extern "C" void kernel_launch(void* const* d_in, const int* in_sizes, int n_in,
                              void* d_out, int out_size, void* d_ws, size_t ws_size,
                              hipStream_t stream) {
    const float* X    = (const float*)d_in[0];  // (8192, 2048)
    const float* Wxh  = (const float*)d_in[1];  // (2048, 2048)
    const float* Whh  = (const float*)d_in[2];  // (2048, 2048)
    const float* bias = (const float*)d_in[3];  // (2048,)
    float* out  = (float*)d_out;
    float* hbuf = (float*)d_ws;                 // 2*H floats

    // Phase 1: U = X @ Wxh^T, written into out[0 .. S*H)
    dim3 ggrid(S / 64, H / 64);
    gemm_xw<<<ggrid, 256, 0, stream>>>(X, Wxh, out);

    // Phase 2: sequential recurrence (cooperative, 1 block/CU)
    void* args[] = {(void*)&out, (void*)&Whh, (void*)&bias, (void*)&hbuf};
    hipLaunchCooperativeKernel((void*)rnn_recur, dim3(NBLK), dim3(256), args, 0, stream);
}

// Round 2
// 85278.131 us; speedup vs baseline: 2.8147x; 2.8147x over previous
//
#include <hip/hip_runtime.h>
#include <math.h>

#define H 2048
#define S 8192
#define RPB 8            // hidden rows per block
#define NBLK (H / RPB)   // 256 blocks = 256 CUs

// ---------------------------------------------------------------------------
// GEMM: U[t][j] = sum_k X[t][k] * Wxh[j][k]   (both row-major, NT layout)
// 64x64 tile, BK=16, 256 threads, 4x4 accumulator per thread, fp32 vector ALU.
// (~1.5 ms, <1% of round-1 runtime — left untouched this round.)
// ---------------------------------------------------------------------------
__global__ __launch_bounds__(256) void gemm_xw(const float* __restrict__ X,
                                               const float* __restrict__ W,
                                               float* __restrict__ U) {
    __shared__ float As[16][64];   // [k][t]
    __shared__ float Bs[16][64];   // [k][j]
    const int tid = threadIdx.x;
    const int t0 = blockIdx.x * 64;
    const int j0 = blockIdx.y * 64;
    const int tx = tid & 15, ty = tid >> 4;

    float acc[4][4] = {};
    const int lr = tid >> 2;        // 0..63 tile row
    const int lk = (tid & 3) * 4;   // 0,4,8,12 k-offset

    for (int k0 = 0; k0 < H; k0 += 16) {
        float4 a = *(const float4*)&X[(size_t)(t0 + lr) * H + k0 + lk];
        float4 b = *(const float4*)&W[(size_t)(j0 + lr) * H + k0 + lk];
        As[lk + 0][lr] = a.x; As[lk + 1][lr] = a.y; As[lk + 2][lr] = a.z; As[lk + 3][lr] = a.w;
        Bs[lk + 0][lr] = b.x; Bs[lk + 1][lr] = b.y; Bs[lk + 2][lr] = b.z; Bs[lk + 3][lr] = b.w;
        __syncthreads();
#pragma unroll
        for (int kk = 0; kk < 16; ++kk) {
            float4 av = *(const float4*)&As[kk][ty * 4];
            float4 bv = *(const float4*)&Bs[kk][tx * 4];
            float aa[4] = {av.x, av.y, av.z, av.w};
            float bb[4] = {bv.x, bv.y, bv.z, bv.w};
#pragma unroll
            for (int i = 0; i < 4; ++i)
#pragma unroll
                for (int j = 0; j < 4; ++j)
                    acc[i][j] += aa[i] * bb[j];
        }
        __syncthreads();
    }
#pragma unroll
    for (int i = 0; i < 4; ++i) {
        float4 v = {acc[i][0], acc[i][1], acc[i][2], acc[i][3]};
        *(float4*)&U[(size_t)(t0 + ty * 4 + i) * H + j0 + tx * 4] = v;
    }
}

// ---------------------------------------------------------------------------
// Init: zero the h double-buffer and the barrier counter (d_ws is poisoned
// 0xAA before every call).
// ---------------------------------------------------------------------------
__global__ void init_ws(float* __restrict__ hbuf, unsigned int* __restrict__ cnt) {
    int i = blockIdx.x * blockDim.x + threadIdx.x;
    if (i < 2 * H) hbuf[i] = 0.0f;
    if (i == 0) *cnt = 0u;
}

// ---------------------------------------------------------------------------
// Persistent recurrent kernel with a hand-rolled agent-scope barrier.
// No cg::grid_group (its sync does a full L2 writeback-invalidate per step
// on multi-XCD gfx950 — 29 us/step measured). Instead:
//   - h published with relaxed AGENT-scope stores (L2-bypassing, sc0 sc1)
//   - one release AGENT-scope fetch_add per block per step (monotonic counter)
//   - spin on relaxed AGENT-scope loads + s_sleep backoff
//   - h re-fetched with relaxed AGENT-scope loads (always coherence-point-fresh)
// Safety of the 2-deep double buffer: a block arrives at barrier t only AFTER
// it copied buffer (t&1) to LDS, so step t+1's overwrite of buffer (t&1)
// cannot race a reader.
// ---------------------------------------------------------------------------
__global__ __launch_bounds__(256) void rnn_recur(float* __restrict__ out,
                                                 const float* __restrict__ Whh,
                                                 const float* __restrict__ bias,
                                                 float* __restrict__ hbuf,
                                                 unsigned int* __restrict__ cnt) {
    __shared__ float Wl[RPB * H];   // 64 KB: this block's 8 rows of W_hh
    __shared__ float hs[H];         // 8 KB: h_{t-1}
    const int tid = threadIdx.x;
    const int r0 = blockIdx.x * RPB;

    // Stage W rows into LDS (once). Block-local; no grid barrier needed.
    {
        const float4* src = (const float4*)&Whh[(size_t)r0 * H];
        float4* dst = (float4*)Wl;
        for (int i = tid; i < RPB * H / 4; i += 256) dst[i] = src[i];
    }

    const int g    = tid >> 5;   // row group 0..7 (aligned 32-lane segments)
    const int lane = tid & 31;
    const int row  = r0 + g;
    const float bb = bias[row];
    const float4* wr = (const float4*)&Wl[g * H];
    const float4* hv = (const float4*)hs;

    for (int t = 0; t < S; ++t) {
        // Fetch h_prev into LDS with L2-bypassing loads (8 floats/thread,
        // coalesced across lanes).
        float* hb_cur = &hbuf[(t & 1) * H];
#pragma unroll
        for (int i = 0; i < 8; ++i) {
            int idx = i * 256 + tid;
            hs[idx] = __hip_atomic_load(&hb_cur[idx], __ATOMIC_RELAXED,
                                        __HIP_MEMORY_SCOPE_AGENT);
        }
        __syncthreads();

        float dot = 0.f;
#pragma unroll
        for (int i = 0; i < 16; ++i) {
            float4 w  = wr[lane + i * 32];
            float4 h4 = hv[lane + i * 32];
            dot += w.x * h4.x + w.y * h4.y + w.z * h4.z + w.w * h4.w;
        }
#pragma unroll
        for (int off = 16; off; off >>= 1)
            dot += __shfl_down(dot, off, 32);

        if (lane == 0) {
            float val = tanhf(dot + out[(size_t)t * H + row] + bb);
            out[(size_t)t * H + row] = val;                 // overwrite U with h_t
            __hip_atomic_store(&hbuf[((t + 1) & 1) * H + row], val,
                               __ATOMIC_RELAXED, __HIP_MEMORY_SCOPE_AGENT);
            if (t == S - 1) out[(size_t)S * H + row] = val; // h_T
        }
        // Each wave drains its vmem (waitcnt before s_barrier), so all 8
        // published h values are globally visible before thread 0 arrives.
        __syncthreads();

        if (tid == 0) {
            __hip_atomic_fetch_add(cnt, 1u, __ATOMIC_RELEASE,
                                   __HIP_MEMORY_SCOPE_AGENT);
            const unsigned int target = (unsigned int)NBLK * (unsigned int)(t + 1);
            while (__hip_atomic_load(cnt, __ATOMIC_RELAXED,
                                     __HIP_MEMORY_SCOPE_AGENT) < target) {
                __builtin_amdgcn_s_sleep(1);
            }
        }
        __syncthreads();
    }
}

extern "C" void kernel_launch(void* const* d_in, const int* in_sizes, int n_in,
                              void* d_out, int out_size, void* d_ws, size_t ws_size,
                              hipStream_t stream) {
    const float* X    = (const float*)d_in[0];  // (8192, 2048)
    const float* Wxh  = (const float*)d_in[1];  // (2048, 2048)
    const float* Whh  = (const float*)d_in[2];  // (2048, 2048)
    const float* bias = (const float*)d_in[3];  // (2048,)
    float* out  = (float*)d_out;
    float* hbuf = (float*)d_ws;                        // 2*H floats
    unsigned int* cnt = (unsigned int*)((char*)d_ws + 2 * H * sizeof(float));

    // Phase 0: zero h0 double-buffer + barrier counter.
    init_ws<<<(2 * H + 255) / 256, 256, 0, stream>>>(hbuf, cnt);

    // Phase 1: U = X @ Wxh^T, written into out[0 .. S*H)
    dim3 ggrid(S / 64, H / 64);
    gemm_xw<<<ggrid, 256, 0, stream>>>(X, Wxh, out);

    // Phase 2: sequential recurrence (cooperative launch for guaranteed
    // co-residency; barrier itself is hand-rolled).
    void* args[] = {(void*)&out, (void*)&Whh, (void*)&bias, (void*)&hbuf, (void*)&cnt};
    hipLaunchCooperativeKernel((void*)rnn_recur, dim3(NBLK), dim3(256), args, 0, stream);
}

// Round 3
// 30216.989 us; speedup vs baseline: 7.9437x; 2.8222x over previous
//
#include <hip/hip_runtime.h>
#include <math.h>

#define H 2048
#define S 8192
#define RPB 8            // hidden rows per block
#define NBLK (H / RPB)   // 256 blocks = 256 CUs

// ---------------------------------------------------------------------------
// GEMM: U[t][j] = sum_k X[t][k] * Wxh[j][k]   (both row-major, NT layout)
// 64x64 tile, BK=16, 256 threads, 4x4 accumulator per thread, fp32 vector ALU.
// ~1.5 ms; not the bottleneck yet.
// ---------------------------------------------------------------------------
__global__ __launch_bounds__(256) void gemm_xw(const float* __restrict__ X,
                                               const float* __restrict__ W,
                                               float* __restrict__ U) {
    __shared__ float As[16][64];   // [k][t]
    __shared__ float Bs[16][64];   // [k][j]
    const int tid = threadIdx.x;
    const int t0 = blockIdx.x * 64;
    const int j0 = blockIdx.y * 64;
    const int tx = tid & 15, ty = tid >> 4;

    float acc[4][4] = {};
    const int lr = tid >> 2;        // 0..63 tile row
    const int lk = (tid & 3) * 4;   // 0,4,8,12 k-offset

    for (int k0 = 0; k0 < H; k0 += 16) {
        float4 a = *(const float4*)&X[(size_t)(t0 + lr) * H + k0 + lk];
        float4 b = *(const float4*)&W[(size_t)(j0 + lr) * H + k0 + lk];
        As[lk + 0][lr] = a.x; As[lk + 1][lr] = a.y; As[lk + 2][lr] = a.z; As[lk + 3][lr] = a.w;
        Bs[lk + 0][lr] = b.x; Bs[lk + 1][lr] = b.y; Bs[lk + 2][lr] = b.z; Bs[lk + 3][lr] = b.w;
        __syncthreads();
#pragma unroll
        for (int kk = 0; kk < 16; ++kk) {
            float4 av = *(const float4*)&As[kk][ty * 4];
            float4 bv = *(const float4*)&Bs[kk][tx * 4];
            float aa[4] = {av.x, av.y, av.z, av.w};
            float bb[4] = {bv.x, bv.y, bv.z, bv.w};
#pragma unroll
            for (int i = 0; i < 4; ++i)
#pragma unroll
                for (int j = 0; j < 4; ++j)
                    acc[i][j] += aa[i] * bb[j];
        }
        __syncthreads();
    }
#pragma unroll
    for (int i = 0; i < 4; ++i) {
        float4 v = {acc[i][0], acc[i][1], acc[i][2], acc[i][3]};
        *(float4*)&U[(size_t)(t0 + ty * 4 + i) * H + j0 + tx * 4] = v;
    }
}

// ---------------------------------------------------------------------------
// Init the tagged h double-buffer. Entry = (tag << 32) | float_bits.
// Buffer 0 gets (tag=0, val=0.0f) == 0ull : h0 = 0 for step 0.
// Buffer 1 gets tag 0 too, which never matches any expected tag >= 1.
// ---------------------------------------------------------------------------
__global__ void init_ws(unsigned long long* __restrict__ hvt) {
    int i = blockIdx.x * blockDim.x + threadIdx.x;
    if (i < 2 * H) hvt[i] = 0ull;
}

// ---------------------------------------------------------------------------
// Persistent recurrent kernel, pure data-flow sync (no barrier, no atomics
// beyond relaxed L2-bypassing loads/stores):
//   publisher (step t): one relaxed agent-scope 8B store of (tag=t+1 | val)
//                       into tagged buffer parity (t+1)&1.
//   consumer  (step t): polls its 8 assigned words of buffer parity t&1
//                       until tag == t, dropping values into LDS as they land.
// Skew bound: publishing tag t+2 requires having consumed all tag t+1, which
// requires all blocks published t+1, which requires all consumed tag t ->
// max skew 1 step -> 2-deep buffer is race-free. Intra-block: ping-pong LDS
// h buffers -> exactly one __syncthreads per step (poll-fill -> dot).
// U (=X@Wxh^T, precomputed into out[]) is loaded at step top so its ~1 us
// latency hides under the poll.
// ---------------------------------------------------------------------------
__global__ __launch_bounds__(256) void rnn_recur(float* __restrict__ out,
                                                 const float* __restrict__ Whh,
                                                 const float* __restrict__ bias,
                                                 unsigned long long* __restrict__ hvt) {
    __shared__ float Wl[RPB * H];   // 64 KB: this block's 8 rows of W_hh
    __shared__ float hs[2][H];      // 16 KB: ping-pong h_{t-1}
    const int tid = threadIdx.x;
    const int r0 = blockIdx.x * RPB;

    // Stage W rows into LDS (once).
    {
        const float4* src = (const float4*)&Whh[(size_t)r0 * H];
        float4* dst = (float4*)Wl;
        for (int i = tid; i < RPB * H / 4; i += 256) dst[i] = src[i];
    }

    const int g    = tid >> 5;   // row group 0..7 (aligned 32-lane segments)
    const int lane = tid & 31;
    const int row  = r0 + g;
    const float bb = bias[row];
    const float4* wr = (const float4*)&Wl[g * H];

    for (int t = 0; t < S; ++t) {
        // Prefetch this step's U value (own rows only; same-block data).
        // Issued before the poll loop -> latency hidden.
        float u_val = out[(size_t)t * H + row];

        // Data-flow wait: gather h_{t-1} (tag == t) into LDS.
        const unsigned int tag = (unsigned int)t;
        unsigned long long* hb = &hvt[(size_t)(t & 1) * H];
        float* hdst = hs[t & 1];
        unsigned int pend = 0xFFu;
        while (pend) {
            unsigned long long vv[8];
#pragma unroll
            for (int i = 0; i < 8; ++i)
                if (pend & (1u << i))
                    vv[i] = __hip_atomic_load(&hb[i * 256 + tid], __ATOMIC_RELAXED,
                                              __HIP_MEMORY_SCOPE_AGENT);
#pragma unroll
            for (int i = 0; i < 8; ++i)
                if (pend & (1u << i)) {
                    if ((unsigned int)(vv[i] >> 32) == tag) {
                        hdst[i * 256 + tid] = __uint_as_float((unsigned int)vv[i]);
                        pend &= ~(1u << i);
                    }
                }
            if (pend) __builtin_amdgcn_s_sleep(1);
        }
        __syncthreads();   // hs[t&1] fully written before any dot reads it

        const float4* hv = (const float4*)hdst;
        float dot = 0.f;
#pragma unroll
        for (int i = 0; i < 16; ++i) {
            float4 w  = wr[lane + i * 32];
            float4 h4 = hv[lane + i * 32];
            dot += w.x * h4.x + w.y * h4.y + w.z * h4.z + w.w * h4.w;
        }
#pragma unroll
        for (int off = 16; off; off >>= 1)
            dot += __shfl_down(dot, off, 32);

        if (lane == 0) {
            float val = tanhf(dot + u_val + bb);
            out[(size_t)t * H + row] = val;                 // overwrite U with h_t
            unsigned long long pk =
                ((unsigned long long)(unsigned int)(t + 1) << 32) |
                (unsigned long long)__float_as_uint(val);
            __hip_atomic_store(&hvt[(size_t)((t + 1) & 1) * H + row], pk,
                               __ATOMIC_RELAXED, __HIP_MEMORY_SCOPE_AGENT);
            if (t == S - 1) out[(size_t)S * H + row] = val; // h_T
        }
        // No trailing barrier: next step's poll writes the OTHER LDS parity,
        // and cross-block progress is gated by the tags themselves.
    }
}

extern "C" void kernel_launch(void* const* d_in, const int* in_sizes, int n_in,
                              void* d_out, int out_size, void* d_ws, size_t ws_size,
                              hipStream_t stream) {
    const float* X    = (const float*)d_in[0];  // (8192, 2048)
    const float* Wxh  = (const float*)d_in[1];  // (2048, 2048)
    const float* Whh  = (const float*)d_in[2];  // (2048, 2048)
    const float* bias = (const float*)d_in[3];  // (2048,)
    float* out = (float*)d_out;
    unsigned long long* hvt = (unsigned long long*)d_ws;   // 2*H tagged values (32 KB)

    // Phase 0: init tagged h buffer (h0 = 0, tag 0).
    init_ws<<<(2 * H + 255) / 256, 256, 0, stream>>>(hvt);

    // Phase 1: U = X @ Wxh^T, written into out[0 .. S*H)
    dim3 ggrid(S / 64, H / 64);
    gemm_xw<<<ggrid, 256, 0, stream>>>(X, Wxh, out);

    // Phase 2: sequential recurrence (cooperative launch for co-residency;
    // sync is pure data-flow on tagged h words).
    void* args[] = {(void*)&out, (void*)&Whh, (void*)&bias, (void*)&hvt};
    hipLaunchCooperativeKernel((void*)rnn_recur, dim3(NBLK), dim3(256), args, 0, stream);
}